// Round 1
// baseline (731.185 us; speedup 1.0000x reference)
//
#include <hip/hip_runtime.h>

// Problem constants (match reference setup_inputs / module constants)
#define EPS_F      1e-4f
#define GRID_RES_F 0.01f
#define ATOL_F     0.01f
#define RTOL_F     1e-5f

static constexpr int V = 1200;
static constexpr int E = 4800;
static constexpr int S = V + E;      // 6000 filtration points
static constexpr int P = 2500;
static constexpr int R = 3;

// Output layout (flat fp32, return order):
//   bars0: [0, 7500)
//   bars1: [7500, 15000)
//   G0:    [15000, 15000+90e6)            (R,P,2S)
//   G1:    [90015000, 180015000)
//   Gc0:   [180015000, 180030000)         (R,P,2)
//   Gc1:   [180030000, 180045000)
static constexpr size_t G0_BASE  = 15000ull;
static constexpr size_t G_ELEMS  = (size_t)R * P * 2 * S;   // 90,000,000
static constexpr size_t GC0_BASE = G0_BASE + 2 * G_ELEMS;   // 180,015,000

// ---------------------------------------------------------------------------
// Kernel 1: build filtration table. filt[j] = (fx, fy, tol_x, tol_y)
// ---------------------------------------------------------------------------
__global__ void build_filt_kernel(const float* __restrict__ f_v,
                                  const int*   __restrict__ edges,
                                  float4*      __restrict__ filt) {
    int j = blockIdx.x * blockDim.x + threadIdx.x;
    if (j >= S) return;
    float fx, fy;
    if (j < V) {
        fx = f_v[2 * j];
        fy = f_v[2 * j + 1];
    } else {
        int e = j - V;
        int a = edges[2 * e];
        int b = edges[2 * e + 1];
        // e_x = max over endpoints of x, + EPS (same for y). Plain fp32 adds.
        fx = __fadd_rn(fmaxf(f_v[2 * a],     f_v[2 * b]),     EPS_F);
        fy = __fadd_rn(fmaxf(f_v[2 * a + 1], f_v[2 * b + 1]), EPS_F);
    }
    // tol = ATOL + RTOL*|f| with NumPy per-op rounding (no fma contraction).
    float tolx = __fadd_rn(ATOL_F, __fmul_rn(RTOL_F, fabsf(fx)));
    float toly = __fadd_rn(ATOL_F, __fmul_rn(RTOL_F, fabsf(fy)));
    filt[j] = make_float4(fx, fy, tolx, toly);
}

// ---------------------------------------------------------------------------
// Kernel 2: one block per (bar-set b, radius r, sample point p) output row.
// Writes 2S floats of G and 2 floats of Gc.
// ---------------------------------------------------------------------------
__device__ __forceinline__ void cell(const float4 f, float psum,
                                     float last_x, float last_y,
                                     const float* lxs, const float* lys,
                                     float& vx, float& vy,
                                     int& aux, int& alx, int& auy, int& aly) {
    float fsum = __fadd_rn(f.x, f.y);
    bool below = fsum < psum;
    bool above = fsum > psum;
    bool hx = false, hy = false;
#pragma unroll
    for (int k = 0; k < 5; ++k) {
        // |line - f| <= tol, line precomputed per row; order matches ref.
        hx = hx || (fabsf(__fsub_rn(lxs[k], f.x)) <= f.z);
        hy = hy || (fabsf(__fsub_rn(lys[k], f.y)) <= f.w);
    }
    bool condx = hx && (f.y <= last_y);
    bool condy = hy && (f.x <= last_x);
    bool ux = condx && above, lx = condx && below;
    bool uy = condy && above, ly = condy && below;
    vx = (ux ? 1.0f : 0.0f) - (lx ? 1.0f : 0.0f);
    vy = (uy ? 1.0f : 0.0f) - (ly ? 1.0f : 0.0f);
    aux |= (int)ux; alx |= (int)lx; auy |= (int)uy; aly |= (int)ly;
}

__global__ __launch_bounds__(256) void grad_kernel(
        const float4* __restrict__ filt,
        const float*  __restrict__ bars0,
        const float*  __restrict__ bars1,
        const float*  __restrict__ sample_pts,
        float*        __restrict__ d_out) {
    const int p = blockIdx.x;   // 0..P-1
    const int r = blockIdx.y;   // 0..R-1
    const int b = blockIdx.z;   // 0..1

    const float* bar = (b == 0) ? bars0 : bars1;
    const float px = sample_pts[2 * p];
    const float py = sample_pts[2 * p + 1];
    const float psum = __fadd_rn(px, py);
    const float s  = __fadd_rn(bar[p * R + r], GRID_RES_F);
    const float s2 = __fmul_rn(2.0f, s);   // exact (x2)

    // line_k = shift_k * s + p  for shift in {-2,-1,0,1,2}; multiply exact.
    float lxs[5], lys[5];
    lxs[0] = __fadd_rn(-s2, px); lxs[1] = __fadd_rn(-s, px); lxs[2] = px;
    lxs[3] = __fadd_rn( s, px);  lxs[4] = __fadd_rn(s2, px);
    lys[0] = __fadd_rn(-s2, py); lys[1] = __fadd_rn(-s, py); lys[2] = py;
    lys[3] = __fadd_rn( s, py);  lys[4] = __fadd_rn(s2, py);
    const float last_x = lxs[4];
    const float last_y = lys[4];

    float* Grow = d_out + G0_BASE + (size_t)b * G_ELEMS
                        + ((size_t)(r * P + p)) * (2 * S);

    __shared__ int sh_flags[4];  // any ux / lx / uy / ly over the row
    if (threadIdx.x < 4) sh_flags[threadIdx.x] = 0;
    __syncthreads();

    int aux = 0, alx = 0, auy = 0, aly = 0;

    // Each thread handles 2 adjacent j per iteration -> one float4 store.
    for (int j0 = threadIdx.x * 2; j0 < S; j0 += 512) {
        float4 f0 = filt[j0];
        float4 f1 = filt[j0 + 1];
        float4 o;
        cell(f0, psum, last_x, last_y, lxs, lys, o.x, o.y, aux, alx, auy, aly);
        cell(f1, psum, last_x, last_y, lxs, lys, o.z, o.w, aux, alx, auy, aly);
        *reinterpret_cast<float4*>(Grow + 2 * j0) = o;
    }

    // Benign-race shared flag writes (all writers store 1).
    if (aux) sh_flags[0] = 1;
    if (alx) sh_flags[1] = 1;
    if (auy) sh_flags[2] = 1;
    if (aly) sh_flags[3] = 1;
    __syncthreads();

    if (threadIdx.x == 0) {
        float cx = sh_flags[0] ? -1.0f : (sh_flags[1] ? 1.0f : 0.0f);
        float cy = sh_flags[2] ? -1.0f : (sh_flags[3] ? 1.0f : 0.0f);
        size_t gc = GC0_BASE + (size_t)b * ((size_t)R * P * 2)
                             + ((size_t)(r * P + p)) * 2;
        d_out[gc]     = cx;
        d_out[gc + 1] = cy;
    }
}

// ---------------------------------------------------------------------------
extern "C" void kernel_launch(void* const* d_in, const int* in_sizes, int n_in,
                              void* d_out, int out_size, void* d_ws, size_t ws_size,
                              hipStream_t stream) {
    const float* f_v        = (const float*)d_in[0];
    const int*   edges      = (const int*)d_in[1];
    const float* bars0      = (const float*)d_in[2];
    const float* bars1      = (const float*)d_in[3];
    const float* sample_pts = (const float*)d_in[4];
    float* out = (float*)d_out;

    float4* filt = (float4*)d_ws;   // S * 16 B = 96 KB scratch

    // bars0 / bars1 pass through to output.
    hipMemcpyAsync(out,        bars0, (size_t)P * R * sizeof(float),
                   hipMemcpyDeviceToDevice, stream);
    hipMemcpyAsync(out + P * R, bars1, (size_t)P * R * sizeof(float),
                   hipMemcpyDeviceToDevice, stream);

    build_filt_kernel<<<(S + 255) / 256, 256, 0, stream>>>(f_v, edges, filt);

    dim3 grid(P, R, 2);
    grad_kernel<<<grid, 256, 0, stream>>>(filt, bars0, bars1, sample_pts, out);
}